// Round 18
// baseline (282.928 us; speedup 1.0000x reference)
//
#include <hip/hip_runtime.h>
#include <hip/hip_bf16.h>

#define NSAMP   480000
#define NFRAMES 3000
#define NFFT    400
#define NFREQ   201
#define NMELS   80
#define HOP     160
#define BATCH   64
#define TT      64
#define TBLK    47                                // ceil(3000/64)
#define NFRAG32 13
#define KS32    25                                // K-steps of 16 (400 exact)
#define MKSTEPS 7
#define PWS     232                               // pw LDS row stride (ushorts)
#define OBS     68                                // mel out LDS row stride (floats)
#define AFRAG_USH (2 * KS32 * 64 * 8)             // 25600 ush = 51.2 KB
#define ACHUNKS   (2 * KS32 * 64)                 // 3200
#define FEAT_ELEMS (BATCH * NMELS * NFRAMES)      // 15,360,000
#define OUT_ELEMS  (FEAT_ELEMS + BATCH * NFRAMES)
#define NF4     (FEAT_ELEMS / 4)                  // 3,840,000
#define NM4     ((BATCH * NFRAMES) / 4)           // 48,000
#define TWO_PI  6.283185307179586f
#define WF32_ELEMS (NFRAG32 * KS32 * 64 * 8)      // 166400
#define MFRAG_ELEMS (5 * MKSTEPS * 64 * 8)        // 17920
#define WF32_BYTES (WF32_ELEMS * 2)
#define MFRAG_BYTES (MFRAG_ELEMS * 2)

typedef __attribute__((ext_vector_type(8))) short bf16x8;
typedef __attribute__((ext_vector_type(8))) ushort ushort8;
typedef __attribute__((ext_vector_type(4))) float f32x4;
typedef __attribute__((ext_vector_type(16))) float f32x16;

static __device__ __forceinline__ ushort f2bf(float x) {
    __hip_bfloat16 h = __float2bfloat16(x);
    return *reinterpret_cast<ushort*>(&h);
}

// wf32: B-frags of DFT W[k][n] (32x32x16): n=nf*32+(l&31) (even n: cos f=n/2, odd: -sin),
//       k=ks*16+8*(l>>5)+j. mfrag: A-frags of MF^T (16x16x32): mel=Mf*16+(l&15), k=freq.
__global__ __launch_bounds__(256)
void fill_tables_k(ushort* __restrict__ wf, ushort* __restrict__ mfr,
                   const float* __restrict__ mf, unsigned* __restrict__ wmax) {
    const int t = blockIdx.x * 256 + threadIdx.x;
    if (t < WF32_ELEMS / 8) {
        const int lane = t & 63;
        const int fk = t >> 6;
        const int ks = fk % KS32;
        const int nf = fk / KS32;
        const int n = nf * 32 + (lane & 31);
        const int kbase = ks * 16 + 8 * (lane >> 5);
        #pragma unroll
        for (int j = 0; j < 8; ++j) {
            const int k = kbase + j;
            float val = 0.f;
            if (n < 2 * NFREQ && k < NFFT) {
                const int f = n >> 1;
                const float win = 0.5f - 0.5f * cosf(TWO_PI * (float)k / (float)NFFT);
                const int r = (f * k) % NFFT;
                const float ph = (float)r * (TWO_PI / (float)NFFT);
                float sv, cv;
                sincosf(ph, &sv, &cv);
                val = (n & 1) ? (-sv * win) : (cv * win);
            }
            wf[(size_t)t * 8 + j] = f2bf(val);
        }
    } else if (t < WF32_ELEMS / 8 + MFRAG_ELEMS / 8) {
        const int u = t - WF32_ELEMS / 8;
        const int lane = u & 63;
        const int fk = u >> 6;
        const int ks = fk % MKSTEPS;
        const int Mf = fk / MKSTEPS;
        const int mel = Mf * 16 + (lane & 15);
        const int kbase = ks * 32 + 8 * (lane >> 4);
        #pragma unroll
        for (int j = 0; j < 8; ++j) {
            const int freq = kbase + j;
            const float val = (freq < NFREQ) ? mf[freq * NMELS + mel] : 0.f;
            mfr[(size_t)u * 8 + j] = f2bf(val);
        }
    }
    if (blockIdx.x == 0 && threadIdx.x < BATCH) wmax[threadIdx.x] = 0u;
}

// ------- Fused: STFT (MFMA) -> power (LDS) -> mel GEMM -> raw log-mel out + max -------
__global__ __launch_bounds__(512, 4)
void stft_mel_k(const float* __restrict__ wav, const ushort* __restrict__ wfrag,
                const ushort* __restrict__ mfrag,
                float* __restrict__ out, unsigned* __restrict__ wmax) {
    __shared__ __align__(16) ushort lds[AFRAG_USH];   // A-frags; pw, then outb alias after

    const int b   = blockIdx.y;
    const int t0  = blockIdx.x * TT;
    const int tid = threadIdx.x;
    const int l   = tid & 63;
    const int wv  = tid >> 6;                      // 0..7
    const float* w = wav + (size_t)b * NSAMP;
    const int g0 = t0 * HOP - (NFFT / 2);

    const ushort* gB0 = wfrag + ((size_t)(wv * KS32) << 9) + (l << 3);
    const ushort* gB1 = wfrag + ((size_t)((wv + 8) * KS32) << 9) + (l << 3);
    const bool hasN1 = (wv < 5);

    // Stage A in MFMA-fragment order; bf16 by TRUNCATION (bit-ops, no cvt chain).
    for (int c = tid; c < ACHUNKS; c += 512) {
        const int cl = c & 63;
        const int fk = c >> 6;
        const int ks = fk % KS32;
        const int m  = fk / KS32;
        const int s0 = g0 + (m * 32 + (cl & 31)) * HOP + 8 * (cl >> 5) + 16 * ks;
        if (s0 >= 0 && s0 + 8 <= NSAMP) {          // fast path (all blocks except 2/47)
            const uint4 v0 = *reinterpret_cast<const uint4*>(w + s0);
            const uint4 v1 = *reinterpret_cast<const uint4*>(w + s0 + 4);
            uint4 pk;
            pk.x = (v0.y & 0xFFFF0000u) | (v0.x >> 16);
            pk.y = (v0.w & 0xFFFF0000u) | (v0.z >> 16);
            pk.z = (v1.y & 0xFFFF0000u) | (v1.x >> 16);
            pk.w = (v1.w & 0xFFFF0000u) | (v1.z >> 16);
            *reinterpret_cast<uint4*>(&lds[(size_t)c * 8]) = pk;
        } else {                                   // edge: per-sample reflect, exact RTN
            ushort8 u;
            #pragma unroll
            for (int j = 0; j < 8; ++j) {
                int idx = s0 + j;
                idx = (idx < 0) ? -idx : idx;
                idx = (idx >= NSAMP) ? (2 * NSAMP - 2 - idx) : idx;
                u[j] = f2bf(w[idx]);
            }
            *reinterpret_cast<ushort8*>(&lds[(size_t)c * 8]) = u;
        }
    }
    __syncthreads();

    f32x16 acc[2][2];
    #pragma unroll
    for (int i = 0; i < 2; ++i)
        #pragma unroll
        for (int m = 0; m < 2; ++m)
            #pragma unroll
            for (int j = 0; j < 16; ++j) acc[i][m][j] = 0.f;

    const int aOff = l << 3;

    // 3-deep rotating prefetch for A (LDS) and B (global/L2).
    bf16x8 A[3][2], B[3][2];
    #pragma unroll
    for (int p = 0; p < 2; ++p) {
        A[p][0] = *reinterpret_cast<const bf16x8*>(lds + ((0 * KS32 + p) << 9) + aOff);
        A[p][1] = *reinterpret_cast<const bf16x8*>(lds + ((1 * KS32 + p) << 9) + aOff);
        B[p][0] = *reinterpret_cast<const bf16x8*>(gB0 + ((size_t)p << 9));
        if (hasN1) B[p][1] = *reinterpret_cast<const bf16x8*>(gB1 + ((size_t)p << 9));
    }

    #pragma unroll
    for (int ks = 0; ks < KS32; ++ks) {
        const int cur = ks % 3;
        if (ks + 2 < KS32) {
            const int nx = (ks + 2) % 3;
            A[nx][0] = *reinterpret_cast<const bf16x8*>(lds + ((0 * KS32 + ks + 2) << 9) + aOff);
            A[nx][1] = *reinterpret_cast<const bf16x8*>(lds + ((1 * KS32 + ks + 2) << 9) + aOff);
            B[nx][0] = *reinterpret_cast<const bf16x8*>(gB0 + ((size_t)(ks + 2) << 9));
            if (hasN1) B[nx][1] = *reinterpret_cast<const bf16x8*>(gB1 + ((size_t)(ks + 2) << 9));
        }
        acc[0][0] = __builtin_amdgcn_mfma_f32_32x32x16_bf16(A[cur][0], B[cur][0], acc[0][0], 0, 0, 0);
        acc[0][1] = __builtin_amdgcn_mfma_f32_32x32x16_bf16(A[cur][1], B[cur][0], acc[0][1], 0, 0, 0);
        if (hasN1) {
            acc[1][0] = __builtin_amdgcn_mfma_f32_32x32x16_bf16(A[cur][0], B[cur][1], acc[1][0], 0, 0, 0);
            acc[1][1] = __builtin_amdgcn_mfma_f32_32x32x16_bf16(A[cur][1], B[cur][1], acc[1][1], 0, 0, 0);
        }
    }
    __syncthreads();   // all A reads done; pw may overwrite lds

    // Zero mel-K padding cols (201..231).
    for (int i = tid; i < TT * 31; i += 512) {
        const int r = i / 31;
        const int cc = 201 + i - r * 31;
        lds[r * PWS + cc] = 0;
    }
    // power = re^2+im^2 (adjacent lanes), scatter pw[frame][freq] bf16.
    // 32x32 C-layout: col=l&31, row=(reg&3)+8*(reg>>2)+4*(l>>5).
    #pragma unroll
    for (int i = 0; i < 2; ++i) {
        if (i == 0 || hasN1) {
            const int nf = wv + 8 * i;
            #pragma unroll
            for (int m = 0; m < 2; ++m) {
                #pragma unroll
                for (int reg = 0; reg < 16; ++reg) {
                    float p = acc[i][m][reg] * acc[i][m][reg];
                    p += __shfl_xor(p, 1);
                    if (!(l & 1)) {
                        const int f = nf * 16 + ((l & 31) >> 1);
                        const int fr = m * 32 + (reg & 3) + 8 * (reg >> 2) + 4 * (l >> 5);
                        if (f < NFREQ) lds[fr * PWS + f] = f2bf(p);
                    }
                }
            }
        }
    }
    __syncthreads();

    // Mel GEMM (16x16x32): 20 tiles (Mf 0..4 x ff 0..3); wave wv takes wv, wv+8, wv+16.
    // log-mel held in registers (static indices).
    float res[3][4];
    float lmax = -3.0e38f;
    #pragma unroll
    for (int q = 0; q < 3; ++q) {
        const int tile = wv + 8 * q;
        if (tile < 20) {
            const int Mf = tile >> 2;
            const int ff = tile & 3;
            f32x4 mc = (f32x4){0.f, 0.f, 0.f, 0.f};
            #pragma unroll
            for (int ks = 0; ks < MKSTEPS; ++ks) {
                const bf16x8 aT = *reinterpret_cast<const bf16x8*>(
                    mfrag + ((size_t)(Mf * MKSTEPS + ks) * 64 + l) * 8);
                const bf16x8 bP = *reinterpret_cast<const bf16x8*>(
                    lds + (ff * 16 + (l & 15)) * PWS + 8 * (l >> 4) + 32 * ks);
                mc = __builtin_amdgcn_mfma_f32_16x16x32_bf16(aT, bP, mc, 0, 0, 0);
            }
            #pragma unroll
            for (int r = 0; r < 4; ++r) {
                const float v = log10f(fmaxf(mc[r], 1e-10f));
                res[q][r] = v;
                const int frame = ff * 16 + (l & 15);
                if (t0 + frame < NFRAMES) lmax = fmaxf(lmax, v);
            }
        }
    }
    __syncthreads();   // all pw reads complete; outb (f32) may overwrite lds

    float* outb = reinterpret_cast<float*>(lds);   // [80][68] = 21.8 KB
    #pragma unroll
    for (int q = 0; q < 3; ++q) {
        const int tile = wv + 8 * q;
        if (tile < 20) {
            const int Mf = tile >> 2;
            const int ff = tile & 3;
            #pragma unroll
            for (int r = 0; r < 4; ++r) {
                const int mel = Mf * 16 + 4 * (l >> 4) + r;
                const int frame = ff * 16 + (l & 15);
                outb[mel * OBS + frame] = res[q][r];
            }
        }
    }
    __syncthreads();

    // Coalesced writeout of raw log-mel: 80 rows x 16 float4 chunks.
    for (int c2 = tid; c2 < NMELS * 16; c2 += 512) {
        const int mel = c2 >> 4;
        const int f4  = (c2 & 15) * 4;
        if (t0 + f4 < NFRAMES) {
            float4 v;
            v.x = outb[mel * OBS + f4];
            v.y = outb[mel * OBS + f4 + 1];
            v.z = outb[mel * OBS + f4 + 2];
            v.w = outb[mel * OBS + f4 + 3];
            *reinterpret_cast<float4*>(
                &out[((size_t)b * NMELS + mel) * NFRAMES + t0 + f4]) = v;
        }
    }

    #pragma unroll
    for (int off = 32; off > 0; off >>= 1)
        lmax = fmaxf(lmax, __shfl_xor(lmax, off));
    if (l == 0) {
        const unsigned bits = __float_as_uint(lmax);
        const unsigned key = bits ^ ((bits & 0x80000000u) ? 0xFFFFFFFFu : 0x80000000u);
        atomicMax(&wmax[b], key);
    }
}

// ---------------- Finalize: float4 clamp+scale + float4 mask ----------------
__global__ __launch_bounds__(256)
void finalize_k(float* __restrict__ out, const unsigned* __restrict__ wmax,
                const int* __restrict__ valid) {
    const int i4 = blockIdx.x * 256 + threadIdx.x;
    if (i4 < NF4) {
        const int b = i4 / (NMELS * NFRAMES / 4);      // 60000 float4 per batch
        const unsigned key = wmax[b];
        const unsigned bits = key ^ ((key & 0x80000000u) ? 0x80000000u : 0xFFFFFFFFu);
        const float mx8 = __uint_as_float(bits) - 8.0f;
        float4 v = *reinterpret_cast<float4*>(&out[(size_t)i4 * 4]);
        v.x = (fmaxf(v.x, mx8) + 4.0f) * 0.25f;
        v.y = (fmaxf(v.y, mx8) + 4.0f) * 0.25f;
        v.z = (fmaxf(v.z, mx8) + 4.0f) * 0.25f;
        v.w = (fmaxf(v.w, mx8) + 4.0f) * 0.25f;
        *reinterpret_cast<float4*>(&out[(size_t)i4 * 4]) = v;
    } else if (i4 < NF4 + NM4) {
        const int j4 = i4 - NF4;
        const int bb = j4 / (NFRAMES / 4);             // 750 float4 per batch
        const int tf0 = (j4 - bb * (NFRAMES / 4)) * 4;
        const int vs = valid[bb];
        float4 m;
        m.x = ((tf0 + 0) * HOP < vs) ? 1.0f : 0.0f;
        m.y = ((tf0 + 1) * HOP < vs) ? 1.0f : 0.0f;
        m.z = ((tf0 + 2) * HOP < vs) ? 1.0f : 0.0f;
        m.w = ((tf0 + 3) * HOP < vs) ? 1.0f : 0.0f;
        *reinterpret_cast<float4*>(&out[FEAT_ELEMS + (size_t)j4 * 4]) = m;
    }
}

extern "C" void kernel_launch(void* const* d_in, const int* in_sizes, int n_in,
                              void* d_out, int out_size, void* d_ws, size_t ws_size,
                              hipStream_t stream) {
    const float* wav   = (const float*)d_in[0];
    const int*   valid = (const int*)d_in[1];
    const float* mf    = (const float*)d_in[2];
    float* out = (float*)d_out;

    ushort*   wfrag = (ushort*)d_ws;
    ushort*   mfrag = (ushort*)((char*)d_ws + WF32_BYTES);
    unsigned* wmax  = (unsigned*)((char*)d_ws + WF32_BYTES + MFRAG_BYTES);

    const int fill_items = WF32_ELEMS / 8 + MFRAG_ELEMS / 8;
    fill_tables_k<<<(fill_items + 255) / 256, 256, 0, stream>>>(wfrag, mfrag, mf, wmax);
    dim3 g(TBLK, BATCH);
    stft_mel_k<<<g, 512, 0, stream>>>(wav, wfrag, mfrag, out, wmax);
    finalize_k<<<(NF4 + NM4 + 255) / 256, 256, 0, stream>>>(out, wmax, valid);
}

// Round 19
// 250.269 us; speedup vs baseline: 1.1305x; 1.1305x over previous
//
#include <hip/hip_runtime.h>
#include <hip/hip_bf16.h>

#define NSAMP   480000
#define NFRAMES 3000
#define NFFT    400
#define NFREQ   201
#define NMELS   80
#define HOP     160
#define BATCH   64
#define TT      64
#define TBLK    47                                // ceil(3000/64)
#define NFRAG32 13
#define KS32    25                                // K-steps of 16 (400 exact)
#define MKSTEPS 7
#define PWS     232                               // pw LDS row stride (ushorts)
#define PROW    208                               // power global row stride (ushorts)
#define OBS     68                                // mel out LDS row stride (floats)
#define AFRAG_USH (2 * KS32 * 64 * 8)             // 25600 ush = 51.2 KB
#define ACHUNKS   (2 * KS32 * 64)                 // 3200
#define FEAT_ELEMS (BATCH * NMELS * NFRAMES)      // 15,360,000
#define OUT_ELEMS  (FEAT_ELEMS + BATCH * NFRAMES)
#define NF4     (FEAT_ELEMS / 4)                  // 3,840,000
#define NM4     ((BATCH * NFRAMES) / 4)           // 48,000
#define TWO_PI  6.283185307179586f
#define WF32_ELEMS (NFRAG32 * KS32 * 64 * 8)      // 166400
#define MFRAG_ELEMS (5 * MKSTEPS * 64 * 8)        // 17920
#define WF32_BYTES (WF32_ELEMS * 2)
#define MFRAG_BYTES (MFRAG_ELEMS * 2)
#define POWER_OFF  (WF32_BYTES + MFRAG_BYTES + 256)
#define POWER_BYTES ((size_t)BATCH * NFRAMES * PROW * 2)   // 79.9 MB
#define NEEDED_WS  (POWER_OFF + POWER_BYTES)

typedef __attribute__((ext_vector_type(8))) short bf16x8;
typedef __attribute__((ext_vector_type(8))) ushort ushort8;
typedef __attribute__((ext_vector_type(4))) float f32x4;
typedef __attribute__((ext_vector_type(16))) float f32x16;

static __device__ __forceinline__ ushort f2bf(float x) {
    __hip_bfloat16 h = __float2bfloat16(x);
    return *reinterpret_cast<ushort*>(&h);
}

// wf32: B-frags of DFT W[k][n] (32x32x16): n=nf*32+(l&31) (even n: cos f=n/2, odd: -sin),
//       k=ks*16+8*(l>>5)+j. mfrag: A-frags of MF^T (16x16x32): mel=Mf*16+(l&15), k=freq.
__global__ __launch_bounds__(256)
void fill_tables_k(ushort* __restrict__ wf, ushort* __restrict__ mfr,
                   const float* __restrict__ mf, unsigned* __restrict__ wmax) {
    const int t = blockIdx.x * 256 + threadIdx.x;
    if (t < WF32_ELEMS / 8) {
        const int lane = t & 63;
        const int fk = t >> 6;
        const int ks = fk % KS32;
        const int nf = fk / KS32;
        const int n = nf * 32 + (lane & 31);
        const int kbase = ks * 16 + 8 * (lane >> 5);
        #pragma unroll
        for (int j = 0; j < 8; ++j) {
            const int k = kbase + j;
            float val = 0.f;
            if (n < 2 * NFREQ && k < NFFT) {
                const int f = n >> 1;
                const float win = 0.5f - 0.5f * cosf(TWO_PI * (float)k / (float)NFFT);
                const int r = (f * k) % NFFT;
                const float ph = (float)r * (TWO_PI / (float)NFFT);
                float sv, cv;
                sincosf(ph, &sv, &cv);
                val = (n & 1) ? (-sv * win) : (cv * win);
            }
            wf[(size_t)t * 8 + j] = f2bf(val);
        }
    } else if (t < WF32_ELEMS / 8 + MFRAG_ELEMS / 8) {
        const int u = t - WF32_ELEMS / 8;
        const int lane = u & 63;
        const int fk = u >> 6;
        const int ks = fk % MKSTEPS;
        const int Mf = fk / MKSTEPS;
        const int mel = Mf * 16 + (lane & 15);
        const int kbase = ks * 32 + 8 * (lane >> 4);
        #pragma unroll
        for (int j = 0; j < 8; ++j) {
            const int freq = kbase + j;
            const float val = (freq < NFREQ) ? mf[freq * NMELS + mel] : 0.f;
            mfr[(size_t)u * 8 + j] = f2bf(val);
        }
    }
    if (blockIdx.x == 0 && threadIdx.x < BATCH) wmax[threadIdx.x] = 0u;
}

// ---------------- K1: STFT -> power. LDS-scatter + coalesced store epilogue. ----------------
__global__ __launch_bounds__(512, 4)   // (512,6) forced VGPR=40 -> 7.6 GB spill traffic (R14)
void stft_power_k(const float* __restrict__ wav, const ushort* __restrict__ wfrag,
                  ushort* __restrict__ pwg) {
    __shared__ __align__(16) ushort lds[AFRAG_USH];   // A-frags; pw (64x232) aliases after

    const int b   = blockIdx.y;
    const int t0  = blockIdx.x * TT;
    const int tid = threadIdx.x;
    const int l   = tid & 63;
    const int wv  = tid >> 6;                      // 0..7
    const float* w = wav + (size_t)b * NSAMP;
    const int g0 = t0 * HOP - (NFFT / 2);

    const ushort* gB0 = wfrag + ((size_t)(wv * KS32) << 9) + (l << 3);
    const ushort* gB1 = wfrag + ((size_t)((wv + 8) * KS32) << 9) + (l << 3);
    const bool hasN1 = (wv < 5);

    // Stage A in MFMA-fragment order; bf16 by TRUNCATION (bit-ops, no cvt chain).
    for (int c = tid; c < ACHUNKS; c += 512) {
        const int cl = c & 63;
        const int fk = c >> 6;
        const int ks = fk % KS32;
        const int m  = fk / KS32;
        const int s0 = g0 + (m * 32 + (cl & 31)) * HOP + 8 * (cl >> 5) + 16 * ks;
        if (s0 >= 0 && s0 + 8 <= NSAMP) {          // fast path (all blocks except 2/47)
            const uint4 v0 = *reinterpret_cast<const uint4*>(w + s0);
            const uint4 v1 = *reinterpret_cast<const uint4*>(w + s0 + 4);
            uint4 pk;
            pk.x = (v0.y & 0xFFFF0000u) | (v0.x >> 16);
            pk.y = (v0.w & 0xFFFF0000u) | (v0.z >> 16);
            pk.z = (v1.y & 0xFFFF0000u) | (v1.x >> 16);
            pk.w = (v1.w & 0xFFFF0000u) | (v1.z >> 16);
            *reinterpret_cast<uint4*>(&lds[(size_t)c * 8]) = pk;
        } else {                                   // edge: per-sample reflect, exact RTN
            ushort8 u;
            #pragma unroll
            for (int j = 0; j < 8; ++j) {
                int idx = s0 + j;
                idx = (idx < 0) ? -idx : idx;
                idx = (idx >= NSAMP) ? (2 * NSAMP - 2 - idx) : idx;
                u[j] = f2bf(w[idx]);
            }
            *reinterpret_cast<ushort8*>(&lds[(size_t)c * 8]) = u;
        }
    }
    __syncthreads();

    f32x16 acc[2][2];
    #pragma unroll
    for (int i = 0; i < 2; ++i)
        #pragma unroll
        for (int m = 0; m < 2; ++m)
            #pragma unroll
            for (int j = 0; j < 16; ++j) acc[i][m][j] = 0.f;

    const int aOff = l << 3;

    // 3-deep rotating prefetch for A (LDS) and B (global/L2).
    bf16x8 A[3][2], B[3][2];
    #pragma unroll
    for (int p = 0; p < 2; ++p) {
        A[p][0] = *reinterpret_cast<const bf16x8*>(lds + ((0 * KS32 + p) << 9) + aOff);
        A[p][1] = *reinterpret_cast<const bf16x8*>(lds + ((1 * KS32 + p) << 9) + aOff);
        B[p][0] = *reinterpret_cast<const bf16x8*>(gB0 + ((size_t)p << 9));
        if (hasN1) B[p][1] = *reinterpret_cast<const bf16x8*>(gB1 + ((size_t)p << 9));
    }

    #pragma unroll
    for (int ks = 0; ks < KS32; ++ks) {
        const int cur = ks % 3;
        if (ks + 2 < KS32) {
            const int nx = (ks + 2) % 3;
            A[nx][0] = *reinterpret_cast<const bf16x8*>(lds + ((0 * KS32 + ks + 2) << 9) + aOff);
            A[nx][1] = *reinterpret_cast<const bf16x8*>(lds + ((1 * KS32 + ks + 2) << 9) + aOff);
            B[nx][0] = *reinterpret_cast<const bf16x8*>(gB0 + ((size_t)(ks + 2) << 9));
            if (hasN1) B[nx][1] = *reinterpret_cast<const bf16x8*>(gB1 + ((size_t)(ks + 2) << 9));
        }
        acc[0][0] = __builtin_amdgcn_mfma_f32_32x32x16_bf16(A[cur][0], B[cur][0], acc[0][0], 0, 0, 0);
        acc[0][1] = __builtin_amdgcn_mfma_f32_32x32x16_bf16(A[cur][1], B[cur][0], acc[0][1], 0, 0, 0);
        if (hasN1) {
            acc[1][0] = __builtin_amdgcn_mfma_f32_32x32x16_bf16(A[cur][0], B[cur][1], acc[1][0], 0, 0, 0);
            acc[1][1] = __builtin_amdgcn_mfma_f32_32x32x16_bf16(A[cur][1], B[cur][1], acc[1][1], 0, 0, 0);
        }
    }
    __syncthreads();   // all A reads done; pw may overwrite lds

    // Zero garbage cols 201..207 of pw.
    for (int i = tid; i < TT * 7; i += 512) {
        const int r = i / 7;
        const int cc = 201 + i - r * 7;
        lds[r * PWS + cc] = 0;
    }
    // power = re^2+im^2 (adjacent lanes), scatter pw[frame][freq] bf16.
    // 32x32 C-layout: col=l&31, row=(reg&3)+8*(reg>>2)+4*(l>>5).
    #pragma unroll
    for (int i = 0; i < 2; ++i) {
        if (i == 0 || hasN1) {
            const int nf = wv + 8 * i;
            #pragma unroll
            for (int m = 0; m < 2; ++m) {
                #pragma unroll
                for (int reg = 0; reg < 16; ++reg) {
                    float p = acc[i][m][reg] * acc[i][m][reg];
                    p += __shfl_xor(p, 1);
                    if (!(l & 1)) {
                        const int f = nf * 16 + ((l & 31) >> 1);
                        const int fr = m * 32 + (reg & 3) + 8 * (reg >> 2) + 4 * (l >> 5);
                        if (f < NFREQ) lds[fr * PWS + f] = f2bf(p);
                    }
                }
            }
        }
    }
    __syncthreads();

    // Coalesced tile store: [64][208] ushort8 chunks (64*26 = 1664 chunks).
    for (int c = tid; c < TT * 26; c += 512) {
        const int row = c / 26;
        const int c8  = (c - row * 26) * 8;
        const int rg  = t0 + row;
        if (rg < NFRAMES) {
            const ushort8 v = *reinterpret_cast<const ushort8*>(&lds[row * PWS + c8]);
            *reinterpret_cast<ushort8*>(&pwg[((size_t)b * NFRAMES + rg) * PROW + c8]) = v;
        }
    }
}

// ---------------- K2: mel GEMM + log10 + max; LDS-staged coalesced out writes ----------------
__global__ __launch_bounds__(256, 5)   // LDS 29.7 KB x5 = 148.5 <= 160; regs ~60 <= 102 cap
void mel_k(const ushort* __restrict__ pwg, const ushort* __restrict__ mfrag,
           float* __restrict__ out, unsigned* __restrict__ wmax) {
    __shared__ __align__(16) ushort pw[TT * PWS];   // 29.7 KB; f32 outb[80][68] aliases after
    float* outb = reinterpret_cast<float*>(pw);

    const int b   = blockIdx.y;
    const int t0  = blockIdx.x * TT;
    const int tid = threadIdx.x;
    const int l   = tid & 63;
    const int wv  = tid >> 6;                      // 0..3

    // Load power tile [64][208] coalesced; rows >=3000 read as zero.
    for (int c = tid; c < TT * 26; c += 256) {
        const int row = c / 26;
        const int c8  = (c - row * 26) * 8;
        const int rg  = t0 + row;
        ushort8 v = (ushort8)(0);
        if (rg < NFRAMES)
            v = *reinterpret_cast<const ushort8*>(&pwg[((size_t)b * NFRAMES + rg) * PROW + c8]);
        *reinterpret_cast<ushort8*>(&pw[row * PWS + c8]) = v;
    }
    // Zero pad cols 208..231.
    for (int i = tid; i < TT * 24; i += 256) {
        const int row = i / 24;
        const int cc = 208 + i - row * 24;
        pw[row * PWS + cc] = 0;
    }
    __syncthreads();

    // Mel GEMM (16x16x32): 20 tiles (Mf 0..4 x ff 0..3); wave wv takes wv+4q, q<5.
    // Results kept in registers (static indices) through the whole loop.
    float res[5][4];
    #pragma unroll
    for (int q = 0; q < 5; ++q) {
        const int tile = wv + 4 * q;
        const int Mf = tile >> 2;
        const int ff = tile & 3;
        f32x4 mc = (f32x4){0.f, 0.f, 0.f, 0.f};
        #pragma unroll
        for (int ks = 0; ks < MKSTEPS; ++ks) {
            const bf16x8 aT = *reinterpret_cast<const bf16x8*>(
                mfrag + ((size_t)(Mf * MKSTEPS + ks) * 64 + l) * 8);
            const bf16x8 bP = *reinterpret_cast<const bf16x8*>(
                pw + (ff * 16 + (l & 15)) * PWS + 8 * (l >> 4) + 32 * ks);
            mc = __builtin_amdgcn_mfma_f32_16x16x32_bf16(aT, bP, mc, 0, 0, 0);
        }
        #pragma unroll
        for (int r = 0; r < 4; ++r) res[q][r] = mc[r];
    }
    __syncthreads();   // all pw reads complete; outb may overwrite

    // log10 + scatter to outb[mel][frame] (stride 68) + guarded max.
    float lmax = -3.0e38f;
    #pragma unroll
    for (int q = 0; q < 5; ++q) {
        const int tile = wv + 4 * q;
        const int Mf = tile >> 2;
        const int ff = tile & 3;
        #pragma unroll
        for (int r = 0; r < 4; ++r) {
            const float v = log10f(fmaxf(res[q][r], 1e-10f));
            const int mel = Mf * 16 + 4 * (l >> 4) + r;
            const int frame = ff * 16 + (l & 15);
            outb[mel * OBS + frame] = v;
            if (t0 + frame < NFRAMES) lmax = fmaxf(lmax, v);
        }
    }
    __syncthreads();

    // Coalesced writeout: 80 rows x 16 float4 chunks = 1280 chunks.
    for (int c2 = tid; c2 < NMELS * 16; c2 += 256) {
        const int mel = c2 >> 4;
        const int f4  = (c2 & 15) * 4;
        if (t0 + f4 < NFRAMES) {   // 3000 and t0,f4 are multiples of 4 -> exact
            float4 v;
            v.x = outb[mel * OBS + f4];
            v.y = outb[mel * OBS + f4 + 1];
            v.z = outb[mel * OBS + f4 + 2];
            v.w = outb[mel * OBS + f4 + 3];
            *reinterpret_cast<float4*>(
                &out[((size_t)b * NMELS + mel) * NFRAMES + t0 + f4]) = v;
        }
    }

    #pragma unroll
    for (int off = 32; off > 0; off >>= 1)
        lmax = fmaxf(lmax, __shfl_xor(lmax, off));
    if (l == 0) {
        const unsigned bits = __float_as_uint(lmax);
        const unsigned key = bits ^ ((bits & 0x80000000u) ? 0xFFFFFFFFu : 0x80000000u);
        atomicMax(&wmax[b], key);
    }
}

// ---------------- Fallback monolith (R9, verified) if ws too small ----------------
__global__ __launch_bounds__(512, 4)
void stft_mel_mono_k(const float* __restrict__ wav, const ushort* __restrict__ wfrag,
                     const ushort* __restrict__ mfrag,
                     float* __restrict__ out, unsigned* __restrict__ wmax) {
    __shared__ __align__(16) ushort lds[AFRAG_USH];
    const int b   = blockIdx.y;
    const int t0  = blockIdx.x * TT;
    const int tid = threadIdx.x;
    const int l   = tid & 63;
    const int wv  = tid >> 6;
    const float* w = wav + (size_t)b * NSAMP;
    const int g0 = t0 * HOP - (NFFT / 2);
    const ushort* gB0 = wfrag + ((size_t)(wv * KS32) << 9) + (l << 3);
    const ushort* gB1 = wfrag + ((size_t)((wv + 8) * KS32) << 9) + (l << 3);
    const bool hasN1 = (wv < 5);
    bf16x8 bb[2][2];
    bb[0][0] = *reinterpret_cast<const bf16x8*>(gB0);
    if (hasN1) bb[0][1] = *reinterpret_cast<const bf16x8*>(gB1);
    for (int c = tid; c < ACHUNKS; c += 512) {
        const int cl = c & 63;
        const int fk = c >> 6;
        const int ks = fk % KS32;
        const int m  = fk / KS32;
        const int s0 = g0 + (m * 32 + (cl & 31)) * HOP + 8 * (cl >> 5) + 16 * ks;
        ushort8 u;
        if (s0 >= 0 && s0 + 8 <= NSAMP) {
            const float4 v0 = *reinterpret_cast<const float4*>(w + s0);
            const float4 v1 = *reinterpret_cast<const float4*>(w + s0 + 4);
            u[0] = f2bf(v0.x); u[1] = f2bf(v0.y); u[2] = f2bf(v0.z); u[3] = f2bf(v0.w);
            u[4] = f2bf(v1.x); u[5] = f2bf(v1.y); u[6] = f2bf(v1.z); u[7] = f2bf(v1.w);
        } else {
            #pragma unroll
            for (int j = 0; j < 8; ++j) {
                int idx = s0 + j;
                idx = (idx < 0) ? -idx : idx;
                idx = (idx >= NSAMP) ? (2 * NSAMP - 2 - idx) : idx;
                u[j] = f2bf(w[idx]);
            }
        }
        *reinterpret_cast<ushort8*>(&lds[(size_t)c * 8]) = u;
    }
    __syncthreads();
    f32x16 acc[2][2];
    #pragma unroll
    for (int i = 0; i < 2; ++i)
        #pragma unroll
        for (int m = 0; m < 2; ++m)
            #pragma unroll
            for (int j = 0; j < 16; ++j) acc[i][m][j] = 0.f;
    const int aOff = l << 3;
    #pragma unroll
    for (int ks = 0; ks < KS32; ++ks) {
        const int cur = ks & 1, nxt = cur ^ 1;
        if (ks + 1 < KS32) {
            bb[nxt][0] = *reinterpret_cast<const bf16x8*>(gB0 + ((size_t)(ks + 1) << 9));
            if (hasN1) bb[nxt][1] = *reinterpret_cast<const bf16x8*>(gB1 + ((size_t)(ks + 1) << 9));
        }
        const bf16x8 a0 = *reinterpret_cast<const bf16x8*>(lds + ((0 * KS32 + ks) << 9) + aOff);
        const bf16x8 a1 = *reinterpret_cast<const bf16x8*>(lds + ((1 * KS32 + ks) << 9) + aOff);
        acc[0][0] = __builtin_amdgcn_mfma_f32_32x32x16_bf16(a0, bb[cur][0], acc[0][0], 0, 0, 0);
        acc[0][1] = __builtin_amdgcn_mfma_f32_32x32x16_bf16(a1, bb[cur][0], acc[0][1], 0, 0, 0);
        if (hasN1) {
            acc[1][0] = __builtin_amdgcn_mfma_f32_32x32x16_bf16(a0, bb[cur][1], acc[1][0], 0, 0, 0);
            acc[1][1] = __builtin_amdgcn_mfma_f32_32x32x16_bf16(a1, bb[cur][1], acc[1][1], 0, 0, 0);
        }
    }
    __syncthreads();
    for (int i = tid; i < TT * 31; i += 512) {
        const int r = i / 31;
        const int cc = 201 + i - r * 31;
        lds[r * PWS + cc] = 0;
    }
    #pragma unroll
    for (int i = 0; i < 2; ++i) {
        if (i == 0 || hasN1) {
            const int nf = wv + 8 * i;
            #pragma unroll
            for (int m = 0; m < 2; ++m) {
                #pragma unroll
                for (int reg = 0; reg < 16; ++reg) {
                    float p = acc[i][m][reg] * acc[i][m][reg];
                    p += __shfl_xor(p, 1);
                    if (!(l & 1)) {
                        const int f = nf * 16 + ((l & 31) >> 1);
                        const int fr = m * 32 + (reg & 3) + 8 * (reg >> 2) + 4 * (l >> 5);
                        if (f < NFREQ) lds[fr * PWS + f] = f2bf(p);
                    }
                }
            }
        }
    }
    __syncthreads();
    float lmax = -3.0e38f;
    #pragma unroll
    for (int q = 0; q < 3; ++q) {
        const int tile = wv + 8 * q;
        if (tile < 20) {
            const int Mf = tile >> 2;
            const int ff = tile & 3;
            f32x4 mc = (f32x4){0.f, 0.f, 0.f, 0.f};
            #pragma unroll
            for (int ks = 0; ks < MKSTEPS; ++ks) {
                const bf16x8 aT = *reinterpret_cast<const bf16x8*>(
                    mfrag + ((size_t)(Mf * MKSTEPS + ks) * 64 + l) * 8);
                const bf16x8 bP = *reinterpret_cast<const bf16x8*>(
                    lds + (ff * 16 + (l & 15)) * PWS + 8 * (l >> 4) + 32 * ks);
                mc = __builtin_amdgcn_mfma_f32_16x16x32_bf16(aT, bP, mc, 0, 0, 0);
            }
            #pragma unroll
            for (int r = 0; r < 4; ++r) {
                const int mel = Mf * 16 + 4 * (l >> 4) + r;
                const int frame = t0 + ff * 16 + (l & 15);
                if (frame < NFRAMES) {
                    const float v = log10f(fmaxf(mc[r], 1e-10f));
                    out[((size_t)b * NMELS + mel) * NFRAMES + frame] = v;
                    lmax = fmaxf(lmax, v);
                }
            }
        }
    }
    #pragma unroll
    for (int off = 32; off > 0; off >>= 1)
        lmax = fmaxf(lmax, __shfl_xor(lmax, off));
    if (l == 0) {
        const unsigned bits = __float_as_uint(lmax);
        const unsigned key = bits ^ ((bits & 0x80000000u) ? 0xFFFFFFFFu : 0x80000000u);
        atomicMax(&wmax[b], key);
    }
}

// ---------------- Finalize: float4 clamp+scale + float4 mask ----------------
__global__ __launch_bounds__(256)
void finalize_k(float* __restrict__ out, const unsigned* __restrict__ wmax,
                const int* __restrict__ valid) {
    const int i4 = blockIdx.x * 256 + threadIdx.x;
    if (i4 < NF4) {
        const int b = i4 / (NMELS * NFRAMES / 4);      // 60000 float4 per batch
        const unsigned key = wmax[b];
        const unsigned bits = key ^ ((key & 0x80000000u) ? 0x80000000u : 0xFFFFFFFFu);
        const float mx8 = __uint_as_float(bits) - 8.0f;
        float4 v = *reinterpret_cast<float4*>(&out[(size_t)i4 * 4]);
        v.x = (fmaxf(v.x, mx8) + 4.0f) * 0.25f;
        v.y = (fmaxf(v.y, mx8) + 4.0f) * 0.25f;
        v.z = (fmaxf(v.z, mx8) + 4.0f) * 0.25f;
        v.w = (fmaxf(v.w, mx8) + 4.0f) * 0.25f;
        *reinterpret_cast<float4*>(&out[(size_t)i4 * 4]) = v;
    } else if (i4 < NF4 + NM4) {
        const int j4 = i4 - NF4;
        const int bb = j4 / (NFRAMES / 4);             // 750 float4 per batch
        const int tf0 = (j4 - bb * (NFRAMES / 4)) * 4;
        const int vs = valid[bb];
        float4 m;
        m.x = ((tf0 + 0) * HOP < vs) ? 1.0f : 0.0f;
        m.y = ((tf0 + 1) * HOP < vs) ? 1.0f : 0.0f;
        m.z = ((tf0 + 2) * HOP < vs) ? 1.0f : 0.0f;
        m.w = ((tf0 + 3) * HOP < vs) ? 1.0f : 0.0f;
        *reinterpret_cast<float4*>(&out[FEAT_ELEMS + (size_t)j4 * 4]) = m;
    }
}

// Scalar finalize for the fallback path (raw log-mel already written by mono).
__global__ __launch_bounds__(256)
void finalize_scalar_k(float* __restrict__ out, const unsigned* __restrict__ wmax,
                       const int* __restrict__ valid) {
    const int i = blockIdx.x * 256 + threadIdx.x;
    if (i < FEAT_ELEMS) {
        const int b = i / (NMELS * NFRAMES);
        const unsigned key = wmax[b];
        const unsigned bits = key ^ ((key & 0x80000000u) ? 0x80000000u : 0xFFFFFFFFu);
        const float mx = __uint_as_float(bits);
        float v = out[i];
        v = fmaxf(v, mx - 8.0f);
        out[i] = (v + 4.0f) * 0.25f;
    } else if (i < OUT_ELEMS) {
        const int j = i - FEAT_ELEMS;
        const int bb = j / NFRAMES;
        const int tf = j - bb * NFRAMES;
        out[i] = (tf * HOP < valid[bb]) ? 1.0f : 0.0f;
    }
}

extern "C" void kernel_launch(void* const* d_in, const int* in_sizes, int n_in,
                              void* d_out, int out_size, void* d_ws, size_t ws_size,
                              hipStream_t stream) {
    const float* wav   = (const float*)d_in[0];
    const int*   valid = (const int*)d_in[1];
    const float* mf    = (const float*)d_in[2];
    float* out = (float*)d_out;

    ushort*   wfrag = (ushort*)d_ws;
    ushort*   mfrag = (ushort*)((char*)d_ws + WF32_BYTES);
    unsigned* wmax  = (unsigned*)((char*)d_ws + WF32_BYTES + MFRAG_BYTES);
    ushort*   pwg   = (ushort*)((char*)d_ws + POWER_OFF);

    const int fill_items = WF32_ELEMS / 8 + MFRAG_ELEMS / 8;
    fill_tables_k<<<(fill_items + 255) / 256, 256, 0, stream>>>(wfrag, mfrag, mf, wmax);
    dim3 g(TBLK, BATCH);
    if (ws_size >= NEEDED_WS) {
        stft_power_k<<<g, 512, 0, stream>>>(wav, wfrag, pwg);
        mel_k<<<g, 256, 0, stream>>>(pwg, mfrag, out, wmax);
        finalize_k<<<(NF4 + NM4 + 255) / 256, 256, 0, stream>>>(out, wmax, valid);
    } else {
        stft_mel_mono_k<<<g, 512, 0, stream>>>(wav, wfrag, mfrag, out, wmax);
        finalize_scalar_k<<<(OUT_ELEMS + 255) / 256, 256, 0, stream>>>(out, wmax, valid);
    }
}

// Round 21
// 213.345 us; speedup vs baseline: 1.3262x; 1.1731x over previous
//
#include <hip/hip_runtime.h>
#include <hip/hip_bf16.h>

#define NSAMP   480000
#define NFRAMES 3000
#define NFFT    400
#define NFREQ   201
#define NMELS   80
#define HOP     160
#define BATCH   64
#define TT      64
#define TBLK    47                                // ceil(3000/64)
#define NPAIR   7                                 // freq frags of 32 (224 >= 201)
#define KF      13                                // folded K-steps of 16 (208 >= 201)
#define MKSTEPS 7
#define PWS     232                               // pw LDS row stride (ushorts)
#define PROW    208                               // power global row stride (ushorts)
#define OBS     68                                // mel out LDS row stride (floats)
#define SREG    (2 * KF * 512)                    // 13312 ush: s-region (2 m x 13 ks chunks)
#define DOFF    SREG
#define LDS_USH (2 * SREG)                        // 26624 ush = 53.2 KB; pw (14848) aliases
#define SCHUNKS (2 * KF * 64)                     // 1664 staging chunks
#define FEAT_ELEMS (BATCH * NMELS * NFRAMES)      // 15,360,000
#define OUT_ELEMS  (FEAT_ELEMS + BATCH * NFRAMES)
#define NF4     (FEAT_ELEMS / 4)
#define NM4     ((BATCH * NFRAMES) / 4)
#define TWO_PI  6.283185307179586f
#define WC_ELEMS (NPAIR * KF * 64 * 8)            // 46592 per table
#define MFRAG_ELEMS (5 * MKSTEPS * 64 * 8)        // 17920
#define WC_BYTES (WC_ELEMS * 2)
#define MFRAG_BYTES (MFRAG_ELEMS * 2)
#define WMAX_OFF  (2 * WC_BYTES + MFRAG_BYTES)            // 222208
#define POWER_OFF (WMAX_OFF + 256)
#define POWER_BYTES ((size_t)BATCH * NFRAMES * PROW * 2)  // 79.9 MB

typedef __attribute__((ext_vector_type(8))) short bf16x8;
typedef __attribute__((ext_vector_type(8))) ushort ushort8;
typedef __attribute__((ext_vector_type(4))) float f32x4;
typedef __attribute__((ext_vector_type(16))) float f32x16;

static __device__ __forceinline__ ushort f2bf(float x) {
    __hip_bfloat16 h = __float2bfloat16(x);
    return *reinterpret_cast<ushort*>(&h);
}
static __device__ __forceinline__ ushort tbf(float x) {     // truncation pack
    return (ushort)(__float_as_uint(x) >> 16);
}
static __device__ __forceinline__ int refl(int idx) {
    idx = (idx < 0) ? -idx : idx;
    return (idx >= NSAMP) ? (2 * NSAMP - 2 - idx) : idx;
}

// wcos/wsin: B-frags (32x32x16) of folded DFT. col f = nf*32+(l&31); km = ks*16+8*(l>>5)+j.
// wcos = win[km]*cos(2pi f km/400); wsin = -win[km]*sin(...); zero outside f<=200, 1<=km<=200.
// km=200 self-pairs in the fold (s[200]=2*x[200]) -> HALVE the cos weight there.
// mfrag: A-frags of MF^T (16x16x32): mel=Mf*16+(l&15), k=freq.
__global__ __launch_bounds__(256)
void fill_tables_k(ushort* __restrict__ wc, ushort* __restrict__ wsn,
                   ushort* __restrict__ mfr, const float* __restrict__ mf,
                   unsigned* __restrict__ wmax) {
    const int t = blockIdx.x * 256 + threadIdx.x;
    if (t < WC_ELEMS / 8) {
        const int lane = t & 63;
        const int fk = t >> 6;
        const int ks = fk % KF;
        const int nf = fk / KF;
        const int f = nf * 32 + (lane & 31);
        const int kbase = ks * 16 + 8 * (lane >> 5);
        #pragma unroll
        for (int j = 0; j < 8; ++j) {
            const int km = kbase + j;
            float vc = 0.f, vs = 0.f;
            if (f <= 200 && km >= 1 && km <= 200) {
                const float win = 0.5f - 0.5f * cosf(TWO_PI * (float)km / (float)NFFT);
                const int r = (f * km) % NFFT;               // exact angle reduction
                const float ph = (float)r * (TWO_PI / (float)NFFT);
                float sv, cv;
                sincosf(ph, &sv, &cv);
                vc = win * cv;
                vs = -win * sv;
                if (km == 200) vc *= 0.5f;                   // Nyquist self-pair fix
            }
            wc [(size_t)t * 8 + j] = f2bf(vc);
            wsn[(size_t)t * 8 + j] = f2bf(vs);
        }
    } else if (t < WC_ELEMS / 8 + MFRAG_ELEMS / 8) {
        const int u = t - WC_ELEMS / 8;
        const int lane = u & 63;
        const int fk = u >> 6;
        const int ks = fk % MKSTEPS;
        const int Mf = fk / MKSTEPS;
        const int mel = Mf * 16 + (lane & 15);
        const int kbase = ks * 32 + 8 * (lane >> 4);
        #pragma unroll
        for (int j = 0; j < 8; ++j) {
            const int freq = kbase + j;
            const float val = (freq < NFREQ) ? mf[freq * NMELS + mel] : 0.f;
            mfr[(size_t)u * 8 + j] = f2bf(val);
        }
    }
    if (blockIdx.x == 0 && threadIdx.x < BATCH) wmax[threadIdx.x] = 0u;
}

// ---- K1: folded STFT (2 GEMMs, K=208) -> power (in-lane) -> coalesced tile store ----
__global__ __launch_bounds__(512, 4)
void stft_power_k(const float* __restrict__ wav, const ushort* __restrict__ wcos,
                  const ushort* __restrict__ wsin, ushort* __restrict__ pwg) {
    __shared__ __align__(16) ushort lds[LDS_USH];   // s|d frags; pw (64x232) aliases after

    const int b   = blockIdx.y;
    const int t0  = blockIdx.x * TT;
    const int tid = threadIdx.x;
    const int l   = tid & 63;
    const int wv  = tid >> 6;                      // 0..7; waves 0..6 compute, 7 stages only
    const float* w = wav + (size_t)b * NSAMP;
    const int g0 = t0 * HOP - (NFFT / 2);

    // Stage folded A: chunk c=(m*13+ks)*64+lane; row r=m*32+(cl&31); km=ks*16+8*(cl>>5)+j.
    // s[km]=x[fs+km]+x[fs+400-km], d[km]=x[fs+km]-x[fs+400-km]; fold in f32, truncate-pack.
    for (int c = tid; c < SCHUNKS; c += 512) {
        const int cl = c & 63;
        const int fk = c >> 6;
        const int ks = fk % KF;
        const int m  = fk / KF;
        const int r  = m * 32 + (cl & 31);
        const int kb = ks * 16 + 8 * (cl >> 5);
        const int fs = g0 + r * HOP;
        ushort8 us, ud;
        if (fs >= 0 && fs + 401 <= NSAMP) {        // interior rows: aligned vector loads
            const float4 f0 = *reinterpret_cast<const float4*>(w + fs + kb);
            const float4 f1 = *reinterpret_cast<const float4*>(w + fs + kb + 4);
            const int ba = fs + 392 - kb;          // 392,kb mult of 8 -> 16B aligned
            const float4 q0 = *reinterpret_cast<const float4*>(w + ba);
            const float4 q1 = *reinterpret_cast<const float4*>(w + ba + 4);
            const float4 q2 = *reinterpret_cast<const float4*>(w + ba + 8);
            const float F[8] = {f0.x, f0.y, f0.z, f0.w, f1.x, f1.y, f1.z, f1.w};
            const float R[8] = {q2.x, q1.w, q1.z, q1.y, q1.x, q0.w, q0.z, q0.y};
            #pragma unroll
            for (int j = 0; j < 8; ++j) {
                us[j] = tbf(F[j] + R[j]);
                ud[j] = tbf(F[j] - R[j]);
            }
        } else {                                   // edge rows: per-sample reflect, RTN
            #pragma unroll
            for (int j = 0; j < 8; ++j) {
                const float a = w[refl(fs + kb + j)];
                const float c2 = w[refl(fs + 400 - kb - j)];
                us[j] = f2bf(a + c2);
                ud[j] = f2bf(a - c2);
            }
        }
        const int base = ((m * KF + ks) << 9) + (cl << 3);
        *reinterpret_cast<ushort8*>(&lds[base]) = us;
        *reinterpret_cast<ushort8*>(&lds[DOFF + base]) = ud;
    }
    __syncthreads();

    f32x16 accC[2], accS[2];
    #pragma unroll
    for (int m = 0; m < 2; ++m)
        #pragma unroll
        for (int j = 0; j < 16; ++j) { accC[m][j] = 0.f; accS[m][j] = 0.f; }

    if (wv < NPAIR) {
        const ushort* gC = wcos + ((size_t)(wv * KF) << 9) + (l << 3);
        const ushort* gS = wsin + ((size_t)(wv * KF) << 9) + (l << 3);
        const int aOff = l << 3;

        // 2-deep prefetch: A (s,d from LDS) and B (cos,sin from L2).
        bf16x8 As[2][2], Ad[2][2], Bc[2], Bs[2];
        #pragma unroll
        for (int m = 0; m < 2; ++m) {
            As[0][m] = *reinterpret_cast<const bf16x8*>(lds + ((m * KF) << 9) + aOff);
            Ad[0][m] = *reinterpret_cast<const bf16x8*>(lds + DOFF + ((m * KF) << 9) + aOff);
        }
        Bc[0] = *reinterpret_cast<const bf16x8*>(gC);
        Bs[0] = *reinterpret_cast<const bf16x8*>(gS);

        #pragma unroll
        for (int ks = 0; ks < KF; ++ks) {
            const int cur = ks & 1, nxt = cur ^ 1;
            if (ks + 1 < KF) {
                #pragma unroll
                for (int m = 0; m < 2; ++m) {
                    As[nxt][m] = *reinterpret_cast<const bf16x8*>(
                        lds + ((m * KF + ks + 1) << 9) + aOff);
                    Ad[nxt][m] = *reinterpret_cast<const bf16x8*>(
                        lds + DOFF + ((m * KF + ks + 1) << 9) + aOff);
                }
                Bc[nxt] = *reinterpret_cast<const bf16x8*>(gC + ((size_t)(ks + 1) << 9));
                Bs[nxt] = *reinterpret_cast<const bf16x8*>(gS + ((size_t)(ks + 1) << 9));
            }
            accC[0] = __builtin_amdgcn_mfma_f32_32x32x16_bf16(As[cur][0], Bc[cur], accC[0], 0, 0, 0);
            accC[1] = __builtin_amdgcn_mfma_f32_32x32x16_bf16(As[cur][1], Bc[cur], accC[1], 0, 0, 0);
            accS[0] = __builtin_amdgcn_mfma_f32_32x32x16_bf16(Ad[cur][0], Bs[cur], accS[0], 0, 0, 0);
            accS[1] = __builtin_amdgcn_mfma_f32_32x32x16_bf16(Ad[cur][1], Bs[cur], accS[1], 0, 0, 0);
        }
    }
    __syncthreads();   // all A reads done; pw may overwrite lds

    // Zero garbage cols 201..207 of pw.
    for (int i = tid; i < TT * 7; i += 512) {
        const int r = i / 7;
        const int cc = 201 + i - r * 7;
        lds[r * PWS + cc] = 0;
    }
    // power = re^2 + im^2, fully in-lane (cos/sin frags share (f,frame) mapping).
    // 32x32 C-layout: col=l&31, row=(reg&3)+8*(reg>>2)+4*(l>>5).
    if (wv < NPAIR) {
        const int f = wv * 32 + (l & 31);
        #pragma unroll
        for (int m = 0; m < 2; ++m) {
            #pragma unroll
            for (int reg = 0; reg < 16; ++reg) {
                const float p = accC[m][reg] * accC[m][reg] + accS[m][reg] * accS[m][reg];
                const int fr = m * 32 + (reg & 3) + 8 * (reg >> 2) + 4 * (l >> 5);
                if (f < NFREQ) lds[fr * PWS + f] = f2bf(p);
            }
        }
    }
    __syncthreads();

    // Coalesced tile store: [64][208] ushort8 chunks.
    for (int c = tid; c < TT * 26; c += 512) {
        const int row = c / 26;
        const int c8  = (c - row * 26) * 8;
        const int rg  = t0 + row;
        if (rg < NFRAMES) {
            const ushort8 v = *reinterpret_cast<const ushort8*>(&lds[row * PWS + c8]);
            *reinterpret_cast<ushort8*>(&pwg[((size_t)b * NFRAMES + rg) * PROW + c8]) = v;
        }
    }
}

// ---------------- K2: mel GEMM + log10 + max; LDS-staged coalesced out writes ----------------
__global__ __launch_bounds__(256, 5)
void mel_k(const ushort* __restrict__ pwg, const ushort* __restrict__ mfrag,
           float* __restrict__ out, unsigned* __restrict__ wmax) {
    __shared__ __align__(16) ushort pw[TT * PWS];   // 29.7 KB; f32 outb[80][68] aliases after
    float* outb = reinterpret_cast<float*>(pw);

    const int b   = blockIdx.y;
    const int t0  = blockIdx.x * TT;
    const int tid = threadIdx.x;
    const int l   = tid & 63;
    const int wv  = tid >> 6;                      // 0..3

    for (int c = tid; c < TT * 26; c += 256) {
        const int row = c / 26;
        const int c8  = (c - row * 26) * 8;
        const int rg  = t0 + row;
        ushort8 v = (ushort8)(0);
        if (rg < NFRAMES)
            v = *reinterpret_cast<const ushort8*>(&pwg[((size_t)b * NFRAMES + rg) * PROW + c8]);
        *reinterpret_cast<ushort8*>(&pw[row * PWS + c8]) = v;
    }
    for (int i = tid; i < TT * 24; i += 256) {
        const int row = i / 24;
        const int cc = 208 + i - row * 24;
        pw[row * PWS + cc] = 0;
    }
    __syncthreads();

    float res[5][4];
    #pragma unroll
    for (int q = 0; q < 5; ++q) {
        const int tile = wv + 4 * q;
        const int Mf = tile >> 2;
        const int ff = tile & 3;
        f32x4 mc = (f32x4){0.f, 0.f, 0.f, 0.f};
        #pragma unroll
        for (int ks = 0; ks < MKSTEPS; ++ks) {
            const bf16x8 aT = *reinterpret_cast<const bf16x8*>(
                mfrag + ((size_t)(Mf * MKSTEPS + ks) * 64 + l) * 8);
            const bf16x8 bP = *reinterpret_cast<const bf16x8*>(
                pw + (ff * 16 + (l & 15)) * PWS + 8 * (l >> 4) + 32 * ks);
            mc = __builtin_amdgcn_mfma_f32_16x16x32_bf16(aT, bP, mc, 0, 0, 0);
        }
        #pragma unroll
        for (int r = 0; r < 4; ++r) res[q][r] = mc[r];
    }
    __syncthreads();

    float lmax = -3.0e38f;
    #pragma unroll
    for (int q = 0; q < 5; ++q) {
        const int tile = wv + 4 * q;
        const int Mf = tile >> 2;
        const int ff = tile & 3;
        #pragma unroll
        for (int r = 0; r < 4; ++r) {
            const float v = log10f(fmaxf(res[q][r], 1e-10f));
            const int mel = Mf * 16 + 4 * (l >> 4) + r;
            const int frame = ff * 16 + (l & 15);
            outb[mel * OBS + frame] = v;
            if (t0 + frame < NFRAMES) lmax = fmaxf(lmax, v);
        }
    }
    __syncthreads();

    for (int c2 = tid; c2 < NMELS * 16; c2 += 256) {
        const int mel = c2 >> 4;
        const int f4  = (c2 & 15) * 4;
        if (t0 + f4 < NFRAMES) {
            float4 v;
            v.x = outb[mel * OBS + f4];
            v.y = outb[mel * OBS + f4 + 1];
            v.z = outb[mel * OBS + f4 + 2];
            v.w = outb[mel * OBS + f4 + 3];
            *reinterpret_cast<float4*>(
                &out[((size_t)b * NMELS + mel) * NFRAMES + t0 + f4]) = v;
        }
    }

    #pragma unroll
    for (int off = 32; off > 0; off >>= 1)
        lmax = fmaxf(lmax, __shfl_xor(lmax, off));
    if (l == 0) {
        const unsigned bits = __float_as_uint(lmax);
        const unsigned key = bits ^ ((bits & 0x80000000u) ? 0xFFFFFFFFu : 0x80000000u);
        atomicMax(&wmax[b], key);
    }
}

// ---------------- Finalize: float4 clamp+scale + float4 mask ----------------
__global__ __launch_bounds__(256)
void finalize_k(float* __restrict__ out, const unsigned* __restrict__ wmax,
                const int* __restrict__ valid) {
    const int i4 = blockIdx.x * 256 + threadIdx.x;
    if (i4 < NF4) {
        const int b = i4 / (NMELS * NFRAMES / 4);
        const unsigned key = wmax[b];
        const unsigned bits = key ^ ((key & 0x80000000u) ? 0x80000000u : 0xFFFFFFFFu);
        const float mx8 = __uint_as_float(bits) - 8.0f;
        float4 v = *reinterpret_cast<float4*>(&out[(size_t)i4 * 4]);
        v.x = (fmaxf(v.x, mx8) + 4.0f) * 0.25f;
        v.y = (fmaxf(v.y, mx8) + 4.0f) * 0.25f;
        v.z = (fmaxf(v.z, mx8) + 4.0f) * 0.25f;
        v.w = (fmaxf(v.w, mx8) + 4.0f) * 0.25f;
        *reinterpret_cast<float4*>(&out[(size_t)i4 * 4]) = v;
    } else if (i4 < NF4 + NM4) {
        const int j4 = i4 - NF4;
        const int bb = j4 / (NFRAMES / 4);
        const int tf0 = (j4 - bb * (NFRAMES / 4)) * 4;
        const int vs = valid[bb];
        float4 m;
        m.x = ((tf0 + 0) * HOP < vs) ? 1.0f : 0.0f;
        m.y = ((tf0 + 1) * HOP < vs) ? 1.0f : 0.0f;
        m.z = ((tf0 + 2) * HOP < vs) ? 1.0f : 0.0f;
        m.w = ((tf0 + 3) * HOP < vs) ? 1.0f : 0.0f;
        *reinterpret_cast<float4*>(&out[FEAT_ELEMS + (size_t)j4 * 4]) = m;
    }
}

extern "C" void kernel_launch(void* const* d_in, const int* in_sizes, int n_in,
                              void* d_out, int out_size, void* d_ws, size_t ws_size,
                              hipStream_t stream) {
    const float* wav   = (const float*)d_in[0];
    const int*   valid = (const int*)d_in[1];
    const float* mf    = (const float*)d_in[2];
    float* out = (float*)d_out;

    ushort*   wcos  = (ushort*)d_ws;
    ushort*   wsin  = (ushort*)((char*)d_ws + WC_BYTES);
    ushort*   mfrag = (ushort*)((char*)d_ws + 2 * WC_BYTES);
    unsigned* wmax  = (unsigned*)((char*)d_ws + WMAX_OFF);
    ushort*   pwg   = (ushort*)((char*)d_ws + POWER_OFF);

    const int fill_items = WC_ELEMS / 8 + MFRAG_ELEMS / 8;
    fill_tables_k<<<(fill_items + 255) / 256, 256, 0, stream>>>(wcos, wsin, mfrag, mf, wmax);
    dim3 g(TBLK, BATCH);
    stft_power_k<<<g, 512, 0, stream>>>(wav, wcos, wsin, pwg);
    mel_k<<<g, 256, 0, stream>>>(pwg, mfrag, out, wmax);
    finalize_k<<<(NF4 + NM4 + 255) / 256, 256, 0, stream>>>(out, wmax, valid);
}